// Round 8
// baseline (112.786 us; speedup 1.0000x reference)
//
#include <hip/hip_runtime.h>

#define BATCH 16384
#define XDIM  133
#define RPB   2       // kernel A: batch rows per block
#define EROW  272     // A: e row pitch bytes (136 halves; 16B-aligned rows)
#define MB    64      // kernel B: batch rows per block
#define CROW  336     // B: cat row pitch bytes (168 halves)
#define TROW  272     // B: t row pitch bytes

// d_ws layout (half-element offsets unless noted)
#define WH_OFF   0        // Wh16   [128][128]
#define W2_OFF   16384    // W2e16  [128][160]  (K padded 133->160, reordered [mf|state|0])
#define WC1_OFF  36864    // Wc1_16 [256][128]
#define WP1_OFF  69632    // Wp1_16 [256][128]
#define WA_OFF   102400   // Wa_e16 [128]
#define WE2_OFF  102528   // packed per-hp: {w00,w10,w01,w11,be0,be1,wam0,wam1} x128 = 1024 halves
#define MFG_OFF  208896   // BYTE offset: mf fp16 [BATCH][128] = 4 MB

typedef __attribute__((ext_vector_type(8))) _Float16 half8;
typedef __attribute__((ext_vector_type(4))) _Float16 half4v;
typedef __attribute__((ext_vector_type(2))) _Float16 half2v;
typedef __attribute__((ext_vector_type(4))) float    f32x4;
typedef __attribute__((ext_vector_type(4))) unsigned int uint4v;

__device__ __forceinline__ float relu(float v) { return fmaxf(v, 0.f); }
__device__ __forceinline__ unsigned short f2h(float f) {
    _Float16 h = (_Float16)f;
    return __builtin_bit_cast(unsigned short, h);
}
__device__ __forceinline__ half2v pk2h(float a, float b) {
    return __builtin_bit_cast(half2v, __builtin_amdgcn_cvt_pkrtz(a, b));
}

// ================= Kernel P: weight fp16 prep =================
__global__ __launch_bounds__(256)
void ac_prep(const float* __restrict__ Wh, const float* __restrict__ W2,
             const float* __restrict__ Wc1, const float* __restrict__ Wp1,
             const float* __restrict__ Wa, const float* __restrict__ We,
             const float* __restrict__ be, unsigned short* __restrict__ wsH)
{
    const int idx = blockIdx.x * 256 + threadIdx.x;
    const int stride = gridDim.x * 256;
    for (int i = idx; i < 128*128; i += stride) wsH[WH_OFF + i] = f2h(Wh[i]);
    for (int i = idx; i < 128*160; i += stride) {
        int o = i / 160, ck = i - o*160;
        float w = (ck < 128) ? W2[o*XDIM + 5 + ck]
                             : ((ck < 133) ? W2[o*XDIM + (ck - 128)] : 0.f);
        wsH[W2_OFF + i] = f2h(w);
    }
    for (int i = idx; i < 256*128; i += stride) wsH[WC1_OFF + i] = f2h(Wc1[i]);
    for (int i = idx; i < 256*128; i += stride) wsH[WP1_OFF + i] = f2h(Wp1[i]);
    for (int i = idx; i < 128;     i += stride) wsH[WA_OFF  + i] = f2h(Wa[i]);
    for (int hp = idx; hp < 128;   hp += stride) {
        wsH[WE2_OFF + hp*8 + 0] = f2h(We[4*hp+0]);   // w00
        wsH[WE2_OFF + hp*8 + 1] = f2h(We[4*hp+2]);   // w10
        wsH[WE2_OFF + hp*8 + 2] = f2h(We[4*hp+1]);   // w01
        wsH[WE2_OFF + hp*8 + 3] = f2h(We[4*hp+3]);   // w11
        wsH[WE2_OFF + hp*8 + 4] = f2h(be[2*hp+0]);
        wsH[WE2_OFF + hp*8 + 5] = f2h(be[2*hp+1]);
        wsH[WE2_OFF + hp*8 + 6] = f2h(Wa[128+2*hp+0]);
        wsH[WE2_OFF + hp*8 + 7] = f2h(Wa[128+2*hp+1]);
    }
}

// ================= Kernel A: e -> softmax -> h-GEMM(MFMA) -> pooled mf =================
// 512 threads (8 waves), RPB=2. M-split in P4: wave>>2 = row, wave&3 = col-set.
__global__ __launch_bounds__(512, 6)
void ac_attn(const float* __restrict__ x,
             const float* __restrict__ bh,  const float* __restrict__ ba,
             const unsigned short* __restrict__ wsH,
             char* __restrict__ mfG)
{
    __shared__ __align__(16) char  eH[RPB * 64 * EROW];   // 34 KB fp16
    __shared__ __align__(16) char  xsH[RPB * 64 * 8];     // 1 KB: (nb0,nb0,nb1,nb1) fp16 splats
    __shared__ __align__(16) float attnS[RPB][64];
    __shared__ __align__(16) float pS[8][64];
    __shared__            float cpart[8];

    const int tid  = threadIdx.x;
    const int lane = tid & 63;
    const int wave = tid >> 6;
    const int b0   = blockIdx.x * RPB;

    // ---- stage nb splats (fp16) ----
    if (tid < 128) {
        int r = tid >> 6, n = tid & 63;
        float2 nb = *(const float2*)(x + (size_t)(b0 + r) * XDIM + 5 + 2*n);
        half2v s0 = pk2h(nb.x, nb.x);
        half2v s1 = pk2h(nb.y, nb.y);
        half4v s; s[0] = s0[0]; s[1] = s0[1]; s[2] = s1[0]; s[3] = s1[1];
        *(half4v*)(xsH + (r*64 + n)*8) = s;
    }
    __syncthreads();

    // ---- P2: e = relu(nb @ We^T + be), packed fp16; em.Wa_m partials ----
    {
        const int hp = lane;
        const int r  = wave >> 2;
        const int nq = wave & 3;
        half8 wp = *(const half8*)(wsH + WE2_OFF + hp*8);
        half2v W0 = {wp[0], wp[1]};
        half2v W1 = {wp[2], wp[3]};
        half2v BE = {wp[4], wp[5]};
        half2v WAM = {wp[6], wp[7]};
        const half2v Z = {(_Float16)0.0f, (_Float16)0.0f};
        float ca = 0.f;
        #pragma unroll
        for (int i = 0; i < 16; ++i) {
            int n = nq*16 + i;
            half4v s = *(const half4v*)(xsH + (r*64 + n)*8);
            half2v s0 = {s[0], s[1]};
            half2v s1 = {s[2], s[3]};
            half2v X = s0*W0 + BE;
            X = s1*W1 + X;
            X = __builtin_elementwise_max(X, Z);
            ca = __builtin_amdgcn_fdot2(X, WAM, ca, false);
            *(half2v*)(eH + (r*64 + n)*EROW + (hp << 2)) = X;
        }
        #pragma unroll
        for (int off = 1; off < 64; off <<= 1) ca += __shfl_xor(ca, off);
        if (lane == 0) cpart[wave] = ca;
    }
    __syncthreads();

    // ---- P3: score partials, wave = (kh<<1)|r, fdot2 ----
    {
        const int r  = wave & 1;
        const int kh = wave >> 1;        // k-quarter (32 halves)
        const int n  = lane;
        const int row = r*64 + n;
        const half2v* wa = (const half2v*)(wsH + WA_OFF) + kh*16;
        float s = 0.f;
        #pragma unroll
        for (int k16 = 0; k16 < 4; ++k16) {
            half8 v = *(const half8*)(eH + row*EROW + kh*64 + k16*16);
            const half2v* v2 = (const half2v*)&v;
            #pragma unroll
            for (int j = 0; j < 4; ++j)
                s = __builtin_amdgcn_fdot2(v2[j], wa[k16*4 + j], s, false);
        }
        pS[wave][n] = s;
    }
    __syncthreads();

    // ---- softmax (waves 0,1) ----
    if (wave < 2) {
        const int r = wave;
        const int n = lane;
        float s = pS[r][n] + pS[2 + r][n] + pS[4 + r][n] + pS[6 + r][n];
        float c = (cpart[r*4+0] + cpart[r*4+1] + cpart[r*4+2] + cpart[r*4+3]) * (1.f/64.f) + ba[0];
        float sc = relu(s + c);
        float m = sc;
        #pragma unroll
        for (int off = 1; off < 64; off <<= 1) m = fmaxf(m, __shfl_xor(m, off));
        float p = __expf(sc - m);
        float sum = p;
        #pragma unroll
        for (int off = 1; off < 64; off <<= 1) sum += __shfl_xor(sum, off);
        attnS[r][n] = p / (sum * 64.f);
    }
    __syncthreads();

    // ---- P4: h-GEMM via MFMA + fused attn pooling (M-split across waves) ----
    {
        const int lo = lane & 15;
        const int g  = lane >> 4;
        const int r  = wave >> 2;        // row of this wave
        const int cs = wave & 3;         // col-set (32 cols)
        const int c0 = cs*32 + lo;
        const int c1 = c0 + 16;
        const unsigned short* WhH = wsH + WH_OFF;
        half8 bfr[2][4];
        #pragma unroll
        for (int kk = 0; kk < 4; ++kk) {
            int kb = kk*32 + g*8;
            bfr[0][kk] = *(const half8*)(WhH + c0*128 + kb);
            bfr[1][kk] = *(const half8*)(WhH + c1*128 + kb);
        }
        const float bh0 = bh[c0], bh1 = bh[c1];

        float mf0 = 0.f, mf1 = 0.f;
        #pragma unroll
        for (int nt = 0; nt < 4; ++nt) {
            const int arow = r*64 + nt*16 + lo;
            half8 af[4];
            #pragma unroll
            for (int kk = 0; kk < 4; ++kk)
                af[kk] = *(const half8*)(eH + arow*EROW + kk*64 + g*16);
            f32x4 acc0 = {0.f, 0.f, 0.f, 0.f};
            f32x4 acc1 = {0.f, 0.f, 0.f, 0.f};
            #pragma unroll
            for (int kk = 0; kk < 4; ++kk) {
                acc0 = __builtin_amdgcn_mfma_f32_16x16x32_f16(af[kk], bfr[0][kk], acc0, 0, 0, 0);
                acc1 = __builtin_amdgcn_mfma_f32_16x16x32_f16(af[kk], bfr[1][kk], acc1, 0, 0, 0);
            }
            f32x4 at4 = *(const f32x4*)&attnS[r][nt*16 + g*4];
            #pragma unroll
            for (int j = 0; j < 4; ++j) {
                mf0 = fmaf(at4[j], relu(acc0[j] + bh0), mf0);
                mf1 = fmaf(at4[j], relu(acc1[j] + bh1), mf1);
            }
        }
        mf0 += __shfl_xor(mf0, 16);  mf0 += __shfl_xor(mf0, 32);
        mf1 += __shfl_xor(mf1, 16);  mf1 += __shfl_xor(mf1, 32);
        if (lane < 16) {
            size_t base = (size_t)(b0 + r) * 128 + cs*32 + lane;
            *(unsigned short*)(mfG + base*2)        = f2h(mf0);
            *(unsigned short*)(mfG + (base + 16)*2) = f2h(mf1);
        }
    }
}

// ================= Kernel B: t-GEMM + heads, MB=64 rows/block =================
__global__ __launch_bounds__(256, 1)
void ac_heads(const float* __restrict__ x, const char* __restrict__ mfG,
              const unsigned short* __restrict__ wsH,
              const float* __restrict__ b2,
              const float* __restrict__ bc1, const float* __restrict__ Wc2,
              const float* __restrict__ bc2,
              const float* __restrict__ bp1, const float* __restrict__ Wp2,
              const float* __restrict__ bp2,
              const float* __restrict__ log_std,
              float* __restrict__ out)
{
    __shared__ __align__(16) char catS[MB * CROW];
    __shared__ __align__(16) char tS[MB * TROW];
    __shared__ float redV [2][MB];
    __shared__ float redM0[2][MB];
    __shared__ float redM1[2][MB];

    const int tid  = threadIdx.x;
    const int lane = tid & 63;
    const int wave = tid >> 6;
    const int lo   = lane & 15;
    const int g    = lane >> 4;
    const int b0   = blockIdx.x * MB;

    for (int i = tid * 16; i < MB * CROW; i += 256 * 16)
        *(uint4v*)(catS + i) = (uint4v){0, 0, 0, 0};
    __syncthreads();
    for (int c = tid; c < MB * 16; c += 256) {
        int row = c >> 4, sl = c & 15;
        uint4v v = *(const uint4v*)(mfG + (size_t)(b0 + row) * 256 + sl * 16);
        *(uint4v*)(catS + row * CROW + sl * 16) = v;
    }
    for (int m = tid; m < MB; m += 256) {
        const float* xr = x + (size_t)(b0 + m) * XDIM;
        #pragma unroll
        for (int k = 0; k < 5; ++k)
            *(unsigned short*)(catS + m * CROW + 256 + 2*k) = f2h(xr[k]);
    }
    __syncthreads();

    // t-GEMM: K=160
    {
        const int o = wave * 32 + lo;
        const unsigned short* W2H = wsH + W2_OFF;
        half8 bw[2][5];
        #pragma unroll
        for (int nt2 = 0; nt2 < 2; ++nt2)
            #pragma unroll
            for (int kk = 0; kk < 5; ++kk)
                bw[nt2][kk] = *(const half8*)(W2H + (size_t)(o + nt2*16)*160 + kk*32 + g*8);
        const float bb0 = b2[o], bb1 = b2[o + 16];
        #pragma unroll
        for (int mt = 0; mt < 4; ++mt) {
            const int arow = mt*16 + lo;
            half8 af[5];
            #pragma unroll
            for (int kk = 0; kk < 5; ++kk)
                af[kk] = *(const half8*)(catS + arow*CROW + kk*64 + g*16);
            f32x4 a0 = {0.f,0.f,0.f,0.f}, a1 = {0.f,0.f,0.f,0.f};
            #pragma unroll
            for (int kk = 0; kk < 5; ++kk) {
                a0 = __builtin_amdgcn_mfma_f32_16x16x32_f16(af[kk], bw[0][kk], a0, 0, 0, 0);
                a1 = __builtin_amdgcn_mfma_f32_16x16x32_f16(af[kk], bw[1][kk], a1, 0, 0, 0);
            }
            #pragma unroll
            for (int j = 0; j < 4; ++j) {
                int m = mt*16 + g*4 + j;
                *(unsigned short*)(tS + m*TROW + o*2)      = f2h(relu(a0[j] + bb0));
                *(unsigned short*)(tS + m*TROW + (o+16)*2) = f2h(relu(a1[j] + bb1));
            }
        }
    }
    __syncthreads();

    // heads
    {
        const bool isval = (wave < 2);
        const unsigned short* W1H = wsH + (isval ? WC1_OFF : WP1_OFF);
        const float* bb = isval ? bc1 : bp1;
        const int obase = (wave & 1) * 128;
        float sA[4][4], sB[4][4];
        #pragma unroll
        for (int mt = 0; mt < 4; ++mt)
            #pragma unroll
            for (int j = 0; j < 4; ++j) { sA[mt][j] = 0.f; sB[mt][j] = 0.f; }

        #pragma unroll
        for (int np = 0; np < 4; ++np) {
            const int oA = obase + np*32 + lo;
            const int oB = oA + 16;
            half8 bf0[4], bf1[4];
            #pragma unroll
            for (int kk = 0; kk < 4; ++kk) {
                bf0[kk] = *(const half8*)(W1H + (size_t)oA*128 + kk*32 + g*8);
                bf1[kk] = *(const half8*)(W1H + (size_t)oB*128 + kk*32 + g*8);
            }
            const float biasA = bb[oA], biasB = bb[oB];
            float wA0, wB0, wA1 = 0.f, wB1 = 0.f;
            if (isval) { wA0 = Wc2[oA]; wB0 = Wc2[oB]; }
            else       { wA0 = Wp2[oA]; wB0 = Wp2[oB]; wA1 = Wp2[256+oA]; wB1 = Wp2[256+oB]; }

            #pragma unroll
            for (int mt = 0; mt < 4; ++mt) {
                const int arow = mt*16 + lo;
                half8 af[4];
                #pragma unroll
                for (int kk = 0; kk < 4; ++kk)
                    af[kk] = *(const half8*)(tS + arow*TROW + kk*64 + g*16);
                f32x4 a0 = {0.f,0.f,0.f,0.f}, a1 = {0.f,0.f,0.f,0.f};
                #pragma unroll
                for (int kk = 0; kk < 4; ++kk) {
                    a0 = __builtin_amdgcn_mfma_f32_16x16x32_f16(af[kk], bf0[kk], a0, 0, 0, 0);
                    a1 = __builtin_amdgcn_mfma_f32_16x16x32_f16(af[kk], bf1[kk], a1, 0, 0, 0);
                }
                #pragma unroll
                for (int j = 0; j < 4; ++j) {
                    float uA = relu(a0[j] + biasA);
                    float uB = relu(a1[j] + biasB);
                    sA[mt][j] += wA0*uA + wB0*uB;
                    sB[mt][j] += wA1*uA + wB1*uB;
                }
            }
        }
        #pragma unroll
        for (int mt = 0; mt < 4; ++mt)
            #pragma unroll
            for (int j = 0; j < 4; ++j) {
                #pragma unroll
                for (int off = 1; off < 16; off <<= 1) {
                    sA[mt][j] += __shfl_xor(sA[mt][j], off);
                    sB[mt][j] += __shfl_xor(sB[mt][j], off);
                }
            }
        if (lo == 0) {
            #pragma unroll
            for (int mt = 0; mt < 4; ++mt)
                #pragma unroll
                for (int j = 0; j < 4; ++j) {
                    int m = mt*16 + g*4 + j;
                    if (isval) redV[wave][m] = sA[mt][j];
                    else { redM0[wave-2][m] = sA[mt][j]; redM1[wave-2][m] = sB[mt][j]; }
                }
        }
    }
    __syncthreads();

    if (tid < MB) {
        const int m = tid;
        const int b = b0 + m;
        out[b*2 + 0]           = redM0[0][m] + redM0[1][m] + bp2[0];
        out[b*2 + 1]           = redM1[0][m] + redM1[1][m] + bp2[1];
        out[2*BATCH + b*2 + 0] = expf(log_std[0]);
        out[2*BATCH + b*2 + 1] = expf(log_std[1]);
        out[4*BATCH + b]       = redV[0][m] + redV[1][m] + bc2[0];
    }
}

extern "C" void kernel_launch(void* const* d_in, const int* in_sizes, int n_in,
                              void* d_out, int out_size, void* d_ws, size_t ws_size,
                              hipStream_t stream) {
    (void)in_sizes; (void)n_in; (void)ws_size; (void)out_size;
    const float* x       = (const float*)d_in[0];
    const float* We      = (const float*)d_in[1];
    const float* be      = (const float*)d_in[2];
    const float* Wh      = (const float*)d_in[3];
    const float* bh      = (const float*)d_in[4];
    const float* Wa      = (const float*)d_in[5];
    const float* ba      = (const float*)d_in[6];
    const float* W2      = (const float*)d_in[7];
    const float* b2      = (const float*)d_in[8];
    const float* Wc1     = (const float*)d_in[9];
    const float* bc1     = (const float*)d_in[10];
    const float* Wc2     = (const float*)d_in[11];
    const float* bc2     = (const float*)d_in[12];
    const float* Wp1     = (const float*)d_in[13];
    const float* bp1     = (const float*)d_in[14];
    const float* Wp2     = (const float*)d_in[15];
    const float* bp2     = (const float*)d_in[16];
    const float* log_std = (const float*)d_in[17];

    unsigned short* wsH = (unsigned short*)d_ws;
    char* mfG = (char*)d_ws + MFG_OFF;

    hipLaunchKernelGGL(ac_prep, dim3(64), dim3(256), 0, stream,
                       Wh, W2, Wc1, Wp1, Wa, We, be, wsH);
    hipLaunchKernelGGL(ac_attn, dim3(BATCH / RPB), dim3(512), 0, stream,
                       x, bh, ba, wsH, mfG);
    hipLaunchKernelGGL(ac_heads, dim3(BATCH / MB), dim3(256), 0, stream,
                       x, mfG, wsH, b2, bc1, Wc2, bc2, bp1, Wp2, bp2,
                       log_std, (float*)d_out);
}

// Round 9
// 80.412 us; speedup vs baseline: 1.4026x; 1.4026x over previous
//
#include <hip/hip_runtime.h>

#define BATCH 16384
#define XDIM  133
#define RPB   2       // kernel A: batch rows per block
#define EROW  272     // A: e row pitch bytes (136 halves; 16B-aligned rows)
#define MB    64      // kernel B: batch rows per block
#define CROW  336     // B: cat row pitch bytes (168 halves)
#define TROW  272     // B: t row pitch bytes

// d_ws layout (half-element offsets unless noted)
#define WH_OFF   0        // Wh16   [128][128]
#define W2_OFF   16384    // W2e16  [128][160]  (K padded 133->160, reordered [mf|state|0])
#define WC1_OFF  36864    // Wc1_16 [256][128]
#define WP1_OFF  69632    // Wp1_16 [256][128]
#define WA_OFF   102400   // Wa_e16 [128]
#define WE2_OFF  102528   // packed per-hp: {w00,w10,w01,w11,be0,be1,wam0,wam1} x128
#define MFG_OFF  208896   // BYTE offset: mf fp16 [BATCH][128] = 4 MB

typedef __attribute__((ext_vector_type(8))) _Float16 half8;
typedef __attribute__((ext_vector_type(4))) _Float16 half4v;
typedef __attribute__((ext_vector_type(2))) _Float16 half2v;
typedef __attribute__((ext_vector_type(4))) float    f32x4;
typedef __attribute__((ext_vector_type(4))) unsigned int uint4v;

__device__ __forceinline__ float relu(float v) { return fmaxf(v, 0.f); }
__device__ __forceinline__ unsigned short f2h(float f) {
    _Float16 h = (_Float16)f;
    return __builtin_bit_cast(unsigned short, h);
}
__device__ __forceinline__ half2v pk2h(float a, float b) {
    return __builtin_bit_cast(half2v, __builtin_amdgcn_cvt_pkrtz(a, b));
}

// ================= Kernel P: weight fp16 prep =================
__global__ __launch_bounds__(256)
void ac_prep(const float* __restrict__ Wh, const float* __restrict__ W2,
             const float* __restrict__ Wc1, const float* __restrict__ Wp1,
             const float* __restrict__ Wa, const float* __restrict__ We,
             const float* __restrict__ be, unsigned short* __restrict__ wsH)
{
    const int idx = blockIdx.x * 256 + threadIdx.x;
    const int stride = gridDim.x * 256;
    for (int i = idx; i < 128*128; i += stride) wsH[WH_OFF + i] = f2h(Wh[i]);
    for (int i = idx; i < 128*160; i += stride) {
        int o = i / 160, ck = i - o*160;
        float w = (ck < 128) ? W2[o*XDIM + 5 + ck]
                             : ((ck < 133) ? W2[o*XDIM + (ck - 128)] : 0.f);
        wsH[W2_OFF + i] = f2h(w);
    }
    for (int i = idx; i < 256*128; i += stride) wsH[WC1_OFF + i] = f2h(Wc1[i]);
    for (int i = idx; i < 256*128; i += stride) wsH[WP1_OFF + i] = f2h(Wp1[i]);
    for (int i = idx; i < 128;     i += stride) wsH[WA_OFF  + i] = f2h(Wa[i]);
    for (int hp = idx; hp < 128;   hp += stride) {
        wsH[WE2_OFF + hp*8 + 0] = f2h(We[4*hp+0]);   // w00
        wsH[WE2_OFF + hp*8 + 1] = f2h(We[4*hp+2]);   // w10
        wsH[WE2_OFF + hp*8 + 2] = f2h(We[4*hp+1]);   // w01
        wsH[WE2_OFF + hp*8 + 3] = f2h(We[4*hp+3]);   // w11
        wsH[WE2_OFF + hp*8 + 4] = f2h(be[2*hp+0]);
        wsH[WE2_OFF + hp*8 + 5] = f2h(be[2*hp+1]);
        wsH[WE2_OFF + hp*8 + 6] = f2h(Wa[128+2*hp+0]);
        wsH[WE2_OFF + hp*8 + 7] = f2h(Wa[128+2*hp+1]);
    }
}

// ================= Kernel A: e -> softmax -> h-GEMM(MFMA) -> pooled mf =================
// R7 structure (256 threads, 4 waves) + R8's packed-fp16 P2 diet.
__global__ __launch_bounds__(256, 4)
void ac_attn(const float* __restrict__ x,
             const float* __restrict__ bh,  const float* __restrict__ ba,
             const unsigned short* __restrict__ wsH,
             char* __restrict__ mfG)
{
    __shared__ __align__(16) char  eH[RPB * 64 * EROW];   // 34 KB fp16
    __shared__ __align__(16) char  xsH[RPB * 64 * 8];     // 1 KB: (nb0,nb0,nb1,nb1) fp16 splats
    __shared__ __align__(16) float attnS[RPB][64];
    __shared__ __align__(16) float mfS[RPB][128];
    __shared__ __align__(16) float pS[4][64];
    __shared__            float cpart[4][RPB];

    const int tid  = threadIdx.x;
    const int lane = tid & 63;
    const int wave = tid >> 6;
    const int b0   = blockIdx.x * RPB;

    // ---- stage nb splats (fp16) ----
    if (tid < 128) {
        int r = tid >> 6, n = tid & 63;
        float2 nb = *(const float2*)(x + (size_t)(b0 + r) * XDIM + 5 + 2*n);
        half2v s0 = pk2h(nb.x, nb.x);
        half2v s1 = pk2h(nb.y, nb.y);
        half4v s; s[0] = s0[0]; s[1] = s0[1]; s[2] = s1[0]; s[3] = s1[1];
        *(half4v*)(xsH + (r*64 + n)*8) = s;
    }
    __syncthreads();

    // ---- P2: e = relu(nb @ We^T + be), packed fp16; em.Wa_m partials ----
    {
        const int hp = lane;
        const int q  = wave;          // n quarter
        half8 wp = *(const half8*)(wsH + WE2_OFF + hp*8);
        half2v W0 = {wp[0], wp[1]};
        half2v W1 = {wp[2], wp[3]};
        half2v BE = {wp[4], wp[5]};
        half2v WAM = {wp[6], wp[7]};
        const half2v Z = {(_Float16)0.0f, (_Float16)0.0f};
        #pragma unroll
        for (int r = 0; r < RPB; ++r) {
            float ca = 0.f;
            #pragma unroll
            for (int i = 0; i < 16; ++i) {
                int n = q*16 + i;
                half4v s = *(const half4v*)(xsH + (r*64 + n)*8);
                half2v s0 = {s[0], s[1]};
                half2v s1 = {s[2], s[3]};
                half2v X = s0*W0 + BE;
                X = s1*W1 + X;
                X = __builtin_elementwise_max(X, Z);
                ca = __builtin_amdgcn_fdot2(X, WAM, ca, false);
                *(half2v*)(eH + (r*64 + n)*EROW + (hp << 2)) = X;
            }
            #pragma unroll
            for (int off = 1; off < 64; off <<= 1) ca += __shfl_xor(ca, off);
            if (lane == 0) cpart[wave][r] = ca;
        }
    }
    __syncthreads();

    // ---- P3: score partials, wave = (kh<<1)|r, fdot2 ----
    {
        const int r  = wave & 1;
        const int kh = wave >> 1;        // k-half (64 halves)
        const int n  = lane;
        const int row = r*64 + n;
        const half2v* wa = (const half2v*)(wsH + WA_OFF) + kh*32;
        float s = 0.f;
        #pragma unroll
        for (int k16 = 0; k16 < 8; ++k16) {
            half8 v = *(const half8*)(eH + row*EROW + kh*128 + k16*16);
            const half2v* v2 = (const half2v*)&v;
            #pragma unroll
            for (int j = 0; j < 4; ++j)
                s = __builtin_amdgcn_fdot2(v2[j], wa[k16*4 + j], s, false);
        }
        pS[wave][n] = s;
    }
    __syncthreads();

    // ---- softmax (waves 0..RPB-1) ----
    if (wave < RPB) {
        const int r = wave;
        const int n = lane;
        float s = pS[r][n] + pS[2 + r][n];
        float c = (cpart[0][r] + cpart[1][r] + cpart[2][r] + cpart[3][r]) * (1.f/64.f) + ba[0];
        float sc = relu(s + c);
        float m = sc;
        #pragma unroll
        for (int off = 1; off < 64; off <<= 1) m = fmaxf(m, __shfl_xor(m, off));
        float p = __expf(sc - m);
        float sum = p;
        #pragma unroll
        for (int off = 1; off < 64; off <<= 1) sum += __shfl_xor(sum, off);
        attnS[r][n] = p / (sum * 64.f);
    }
    __syncthreads();

    // ---- P4: h-GEMM via MFMA (fp16 weights preconverted) + fused attn pooling ----
    {
        const int lo = lane & 15;
        const int g  = lane >> 4;
        const int c0 = wave*32 + lo;
        const int c1 = c0 + 16;
        const unsigned short* WhH = wsH + WH_OFF;
        half8 bfr[2][4];
        #pragma unroll
        for (int kk = 0; kk < 4; ++kk) {
            int kb = kk*32 + g*8;
            bfr[0][kk] = *(const half8*)(WhH + c0*128 + kb);
            bfr[1][kk] = *(const half8*)(WhH + c1*128 + kb);
        }
        const float bh0 = bh[c0], bh1 = bh[c1];

        #pragma unroll
        for (int r = 0; r < RPB; ++r) {
            float mf0 = 0.f, mf1 = 0.f;
            #pragma unroll
            for (int nt = 0; nt < 4; ++nt) {
                const int arow = r*64 + nt*16 + lo;
                half8 af[4];
                #pragma unroll
                for (int kk = 0; kk < 4; ++kk)
                    af[kk] = *(const half8*)(eH + arow*EROW + kk*64 + g*16);
                f32x4 acc0 = {0.f, 0.f, 0.f, 0.f};
                f32x4 acc1 = {0.f, 0.f, 0.f, 0.f};
                #pragma unroll
                for (int kk = 0; kk < 4; ++kk) {
                    acc0 = __builtin_amdgcn_mfma_f32_16x16x32_f16(af[kk], bfr[0][kk], acc0, 0, 0, 0);
                    acc1 = __builtin_amdgcn_mfma_f32_16x16x32_f16(af[kk], bfr[1][kk], acc1, 0, 0, 0);
                }
                f32x4 at4 = *(const f32x4*)&attnS[r][nt*16 + g*4];
                #pragma unroll
                for (int j = 0; j < 4; ++j) {
                    mf0 = fmaf(at4[j], relu(acc0[j] + bh0), mf0);
                    mf1 = fmaf(at4[j], relu(acc1[j] + bh1), mf1);
                }
            }
            mf0 += __shfl_xor(mf0, 16);  mf0 += __shfl_xor(mf0, 32);
            mf1 += __shfl_xor(mf1, 16);  mf1 += __shfl_xor(mf1, 32);
            if (lane < 16) {
                mfS[r][wave*32 + lane]      = mf0;
                mfS[r][wave*32 + 16 + lane] = mf1;
            }
        }
    }
    __syncthreads();

    // ---- write mf (fp16) to workspace ----
    if (tid < RPB * 64) {
        int r = tid >> 6, c = tid & 63;
        *(half2v*)(mfG + ((size_t)(b0 + r) * 128 + 2*c) * 2) = pk2h(mfS[r][2*c], mfS[r][2*c+1]);
    }
}

// ================= Kernel B: t-GEMM + heads, MB=64 rows/block =================
__global__ __launch_bounds__(256, 1)
void ac_heads(const float* __restrict__ x, const char* __restrict__ mfG,
              const unsigned short* __restrict__ wsH,
              const float* __restrict__ b2,
              const float* __restrict__ bc1, const float* __restrict__ Wc2,
              const float* __restrict__ bc2,
              const float* __restrict__ bp1, const float* __restrict__ Wp2,
              const float* __restrict__ bp2,
              const float* __restrict__ log_std,
              float* __restrict__ out)
{
    __shared__ __align__(16) char catS[MB * CROW];
    __shared__ __align__(16) char tS[MB * TROW];
    __shared__ float redV [2][MB];
    __shared__ float redM0[2][MB];
    __shared__ float redM1[2][MB];

    const int tid  = threadIdx.x;
    const int lane = tid & 63;
    const int wave = tid >> 6;
    const int lo   = lane & 15;
    const int g    = lane >> 4;
    const int b0   = blockIdx.x * MB;

    for (int i = tid * 16; i < MB * CROW; i += 256 * 16)
        *(uint4v*)(catS + i) = (uint4v){0, 0, 0, 0};
    __syncthreads();
    for (int c = tid; c < MB * 16; c += 256) {
        int row = c >> 4, sl = c & 15;
        uint4v v = *(const uint4v*)(mfG + (size_t)(b0 + row) * 256 + sl * 16);
        *(uint4v*)(catS + row * CROW + sl * 16) = v;
    }
    for (int m = tid; m < MB; m += 256) {
        const float* xr = x + (size_t)(b0 + m) * XDIM;
        #pragma unroll
        for (int k = 0; k < 5; ++k)
            *(unsigned short*)(catS + m * CROW + 256 + 2*k) = f2h(xr[k]);
    }
    __syncthreads();

    // t-GEMM: K=160
    {
        const int o = wave * 32 + lo;
        const unsigned short* W2H = wsH + W2_OFF;
        half8 bw[2][5];
        #pragma unroll
        for (int nt2 = 0; nt2 < 2; ++nt2)
            #pragma unroll
            for (int kk = 0; kk < 5; ++kk)
                bw[nt2][kk] = *(const half8*)(W2H + (size_t)(o + nt2*16)*160 + kk*32 + g*8);
        const float bb0 = b2[o], bb1 = b2[o + 16];
        #pragma unroll
        for (int mt = 0; mt < 4; ++mt) {
            const int arow = mt*16 + lo;
            half8 af[5];
            #pragma unroll
            for (int kk = 0; kk < 5; ++kk)
                af[kk] = *(const half8*)(catS + arow*CROW + kk*64 + g*16);
            f32x4 a0 = {0.f,0.f,0.f,0.f}, a1 = {0.f,0.f,0.f,0.f};
            #pragma unroll
            for (int kk = 0; kk < 5; ++kk) {
                a0 = __builtin_amdgcn_mfma_f32_16x16x32_f16(af[kk], bw[0][kk], a0, 0, 0, 0);
                a1 = __builtin_amdgcn_mfma_f32_16x16x32_f16(af[kk], bw[1][kk], a1, 0, 0, 0);
            }
            #pragma unroll
            for (int j = 0; j < 4; ++j) {
                int m = mt*16 + g*4 + j;
                *(unsigned short*)(tS + m*TROW + o*2)      = f2h(relu(a0[j] + bb0));
                *(unsigned short*)(tS + m*TROW + (o+16)*2) = f2h(relu(a1[j] + bb1));
            }
        }
    }
    __syncthreads();

    // heads
    {
        const bool isval = (wave < 2);
        const unsigned short* W1H = wsH + (isval ? WC1_OFF : WP1_OFF);
        const float* bb = isval ? bc1 : bp1;
        const int obase = (wave & 1) * 128;
        float sA[4][4], sB[4][4];
        #pragma unroll
        for (int mt = 0; mt < 4; ++mt)
            #pragma unroll
            for (int j = 0; j < 4; ++j) { sA[mt][j] = 0.f; sB[mt][j] = 0.f; }

        #pragma unroll
        for (int np = 0; np < 4; ++np) {
            const int oA = obase + np*32 + lo;
            const int oB = oA + 16;
            half8 bf0[4], bf1[4];
            #pragma unroll
            for (int kk = 0; kk < 4; ++kk) {
                bf0[kk] = *(const half8*)(W1H + (size_t)oA*128 + kk*32 + g*8);
                bf1[kk] = *(const half8*)(W1H + (size_t)oB*128 + kk*32 + g*8);
            }
            const float biasA = bb[oA], biasB = bb[oB];
            float wA0, wB0, wA1 = 0.f, wB1 = 0.f;
            if (isval) { wA0 = Wc2[oA]; wB0 = Wc2[oB]; }
            else       { wA0 = Wp2[oA]; wB0 = Wp2[oB]; wA1 = Wp2[256+oA]; wB1 = Wp2[256+oB]; }

            #pragma unroll
            for (int mt = 0; mt < 4; ++mt) {
                const int arow = mt*16 + lo;
                half8 af[4];
                #pragma unroll
                for (int kk = 0; kk < 4; ++kk)
                    af[kk] = *(const half8*)(tS + arow*TROW + kk*64 + g*16);
                f32x4 a0 = {0.f,0.f,0.f,0.f}, a1 = {0.f,0.f,0.f,0.f};
                #pragma unroll
                for (int kk = 0; kk < 4; ++kk) {
                    a0 = __builtin_amdgcn_mfma_f32_16x16x32_f16(af[kk], bf0[kk], a0, 0, 0, 0);
                    a1 = __builtin_amdgcn_mfma_f32_16x16x32_f16(af[kk], bf1[kk], a1, 0, 0, 0);
                }
                #pragma unroll
                for (int j = 0; j < 4; ++j) {
                    float uA = relu(a0[j] + biasA);
                    float uB = relu(a1[j] + biasB);
                    sA[mt][j] += wA0*uA + wB0*uB;
                    sB[mt][j] += wA1*uA + wB1*uB;
                }
            }
        }
        #pragma unroll
        for (int mt = 0; mt < 4; ++mt)
            #pragma unroll
            for (int j = 0; j < 4; ++j) {
                #pragma unroll
                for (int off = 1; off < 16; off <<= 1) {
                    sA[mt][j] += __shfl_xor(sA[mt][j], off);
                    sB[mt][j] += __shfl_xor(sB[mt][j], off);
                }
            }
        if (lo == 0) {
            #pragma unroll
            for (int mt = 0; mt < 4; ++mt)
                #pragma unroll
                for (int j = 0; j < 4; ++j) {
                    int m = mt*16 + g*4 + j;
                    if (isval) redV[wave][m] = sA[mt][j];
                    else { redM0[wave-2][m] = sA[mt][j]; redM1[wave-2][m] = sB[mt][j]; }
                }
        }
    }
    __syncthreads();

    if (tid < MB) {
        const int m = tid;
        const int b = b0 + m;
        out[b*2 + 0]           = redM0[0][m] + redM0[1][m] + bp2[0];
        out[b*2 + 1]           = redM1[0][m] + redM1[1][m] + bp2[1];
        out[2*BATCH + b*2 + 0] = expf(log_std[0]);
        out[2*BATCH + b*2 + 1] = expf(log_std[1]);
        out[4*BATCH + b]       = redV[0][m] + redV[1][m] + bc2[0];
    }
}

extern "C" void kernel_launch(void* const* d_in, const int* in_sizes, int n_in,
                              void* d_out, int out_size, void* d_ws, size_t ws_size,
                              hipStream_t stream) {
    (void)in_sizes; (void)n_in; (void)ws_size; (void)out_size;
    const float* x       = (const float*)d_in[0];
    const float* We      = (const float*)d_in[1];
    const float* be      = (const float*)d_in[2];
    const float* Wh      = (const float*)d_in[3];
    const float* bh      = (const float*)d_in[4];
    const float* Wa      = (const float*)d_in[5];
    const float* ba      = (const float*)d_in[6];
    const float* W2      = (const float*)d_in[7];
    const float* b2      = (const float*)d_in[8];
    const float* Wc1     = (const float*)d_in[9];
    const float* bc1     = (const float*)d_in[10];
    const float* Wc2     = (const float*)d_in[11];
    const float* bc2     = (const float*)d_in[12];
    const float* Wp1     = (const float*)d_in[13];
    const float* bp1     = (const float*)d_in[14];
    const float* Wp2     = (const float*)d_in[15];
    const float* bp2     = (const float*)d_in[16];
    const float* log_std = (const float*)d_in[17];

    unsigned short* wsH = (unsigned short*)d_ws;
    char* mfG = (char*)d_ws + MFG_OFF;

    hipLaunchKernelGGL(ac_prep, dim3(64), dim3(256), 0, stream,
                       Wh, W2, Wc1, Wp1, Wa, We, be, wsH);
    hipLaunchKernelGGL(ac_attn, dim3(BATCH / RPB), dim3(256), 0, stream,
                       x, bh, ba, wsH, mfG);
    hipLaunchKernelGGL(ac_heads, dim3(BATCH / MB), dim3(256), 0, stream,
                       x, mfG, wsH, b2, bc1, Wc2, bc2, bp1, Wp2, bp2,
                       log_std, (float*)d_out);
}